// Round 2
// 390.115 us; speedup vs baseline: 1.0566x; 1.0566x over previous
//
#include <hip/hip_runtime.h>

typedef _Float16 half8 __attribute__((ext_vector_type(8)));
typedef _Float16 half4 __attribute__((ext_vector_type(4)));
typedef short short8 __attribute__((ext_vector_type(8)));
typedef unsigned short ushort4v __attribute__((ext_vector_type(4)));
typedef float floatx4 __attribute__((ext_vector_type(4)));

#define ASYNC16(g, l) __builtin_amdgcn_global_load_lds( \
    (const __attribute__((address_space(1))) void*)(g),  \
    (__attribute__((address_space(3))) void*)(l), 16, 0, 0)

__device__ inline unsigned short f2bf(float f) {          // RNE fp32->bf16
    unsigned u = __builtin_bit_cast(unsigned, f);
    u += 0x7fff + ((u >> 16) & 1);
    return (unsigned short)(u >> 16);
}
__device__ inline float bf2f(unsigned short b) {
    unsigned u = (unsigned)b << 16;
    return __builtin_bit_cast(float, u);
}

// ---------------------------------------------------------------------------
// fp32 -> fp16 bulk convert (vectorized, grid-stride)
// ---------------------------------------------------------------------------
__global__ void cvt_f2h(const float* __restrict__ in, _Float16* __restrict__ out, int n4)
{
    int i = blockIdx.x * blockDim.x + threadIdx.x;
    const int stride = gridDim.x * blockDim.x;
    for (; i < n4; i += stride) {
        float4 v = ((const float4*)in)[i];
        half4 h = { (_Float16)v.x, (_Float16)v.y, (_Float16)v.z, (_Float16)v.w };
        ((half4*)out)[i] = h;
    }
}

// ---------------------------------------------------------------------------
// W [K=1024][N=1024] fp32  ->  Wt [N][K] fp16   (z = which of Wq/Wk/Wv)
// ---------------------------------------------------------------------------
__global__ void transpose_w(const float* __restrict__ Wq, const float* __restrict__ Wk,
                            const float* __restrict__ Wv, _Float16* __restrict__ Wt)
{
    const float* W = (blockIdx.z == 0) ? Wq : (blockIdx.z == 1) ? Wk : Wv;
    _Float16* out = Wt + (size_t)blockIdx.z * 1024 * 1024;
    __shared__ float t[32][33];
    const int tx = threadIdx.x, ty = threadIdx.y;     // (32,8)
    const int k0 = blockIdx.x * 32, n0 = blockIdx.y * 32;
#pragma unroll
    for (int i = 0; i < 32; i += 8)
        t[ty + i][tx] = W[(size_t)(k0 + ty + i) * 1024 + n0 + tx];   // t[k][n]
    __syncthreads();
#pragma unroll
    for (int i = 0; i < 32; i += 8)
        out[(size_t)(n0 + ty + i) * 1024 + k0 + tx] = (_Float16)t[tx][ty + i];  // out[n][k]=W[k][n]
}

// ---------------------------------------------------------------------------
// 256x256 8-phase counted-vmcnt GEMM core (T3+T4+T5), BK=64, 512 threads.
// Stage-placement ledger (R2 fix — write-after-last-read + land-before-read):
//   buf0-B last read ph2 -> overwrite from ph3;  buf0-A last read ph3 -> from ph5
//   buf1-B last read ph6 -> overwrite from ph7;  buf1-A last read ph7 -> from ph8
//   vmcnt(4) @ph4: all but 2 newest stages landed -> buf1 tile complete pre-ph5
//   vmcnt(8) @ph8: all but 4 newest (the buf1 stages) landed -> buf0 complete
// ---------------------------------------------------------------------------
template<bool BF16>
__device__ __forceinline__ floatx4 MF(short8 a, short8 b, floatx4 c) {
    if constexpr (BF16)
        return __builtin_amdgcn_mfma_f32_16x16x32_bf16(a, b, c, 0, 0, 0);
    else
        return __builtin_amdgcn_mfma_f32_16x16x32_f16(
            __builtin_bit_cast(half8, a), __builtin_bit_cast(half8, b), c, 0, 0, 0);
}

template<int LDA, int LDB, int NT, bool BF16>
__device__ __forceinline__ void gemm_core8(
    const unsigned short* __restrict__ Ab, const unsigned short* __restrict__ Bb,
    unsigned short* sA, unsigned short* sB, floatx4 (&acc)[8][4])
{
    const int tid = threadIdx.x;
    const int lane = tid & 63, quad = lane >> 4, l15 = lane & 15;
    const int wave = tid >> 6;
    const int wm = wave >> 2, wn = wave & 3;
    const int rowbase = wm * 128, colbase = wn * 64;
    const int sw = l15 & 7;

    long srcA[2], srcB[2];
    int dst[2];
#pragma unroll
    for (int u = 0; u < 2; ++u) {
        const int c = tid + u * 512;
        const int row = c >> 3;                 // row within 128-row half
        const int g = (c & 7) ^ (row & 7);      // pre-swizzled global chunk
        srcA[u] = (long)row * LDA + g * 8;
        srcB[u] = (long)row * LDB + g * 8;
        dst[u] = c * 16;                        // linear LDS bytes within half
    }

    short8 a[4][2], b[2][2][2];

    auto stgA = [&](int p, int h, int kt) {
#pragma unroll
        for (int u = 0; u < 2; ++u)
            ASYNC16(Ab + (long)kt * 64 + (long)h * (128 * LDA) + srcA[u],
                    (char*)sA + p * 32768 + h * 16384 + dst[u]);
    };
    auto stgB = [&](int p, int h, int kt) {
#pragma unroll
        for (int u = 0; u < 2; ++u)
            ASYNC16(Bb + (long)kt * 64 + (long)h * (128 * LDB) + srcB[u],
                    (char*)sB + p * 32768 + h * 16384 + dst[u]);
    };
    auto rdA = [&](int mq, int p) {
#pragma unroll
        for (int ii = 0; ii < 4; ++ii) {
            const int row = rowbase + (mq * 4 + ii) * 16 + l15;
#pragma unroll
            for (int kk = 0; kk < 2; ++kk)
                a[ii][kk] = *(const short8*)(sA + p * 16384 + row * 64 +
                                             (((kk * 4 + quad) ^ sw) * 8));
        }
    };
    auto rdB = [&](int nq, int p) {
#pragma unroll
        for (int jj = 0; jj < 2; ++jj) {
            const int row = colbase + (nq * 2 + jj) * 16 + l15;
#pragma unroll
            for (int kk = 0; kk < 2; ++kk)
                b[nq][jj][kk] = *(const short8*)(sB + p * 16384 + row * 64 +
                                                 (((kk * 4 + quad) ^ sw) * 8));
        }
    };
    auto mm = [&](int mq, int nq) {
        __builtin_amdgcn_s_setprio(1);
#pragma unroll
        for (int ii = 0; ii < 4; ++ii)
#pragma unroll
            for (int jj = 0; jj < 2; ++jj)
#pragma unroll
                for (int kk = 0; kk < 2; ++kk)
                    acc[mq * 4 + ii][nq * 2 + jj] =
                        MF<BF16>(a[ii][kk], b[nq][jj][kk], acc[mq * 4 + ii][nq * 2 + jj]);
        __builtin_amdgcn_s_setprio(0);
    };
    auto bar   = [] { __builtin_amdgcn_s_barrier(); };
    auto lgkm0 = [] { asm volatile("s_waitcnt lgkmcnt(0)" ::: "memory");
                      __builtin_amdgcn_sched_barrier(0); };
    auto vm4   = [] { asm volatile("s_waitcnt vmcnt(4)" ::: "memory"); };
    auto vm8   = [] { asm volatile("s_waitcnt vmcnt(8)" ::: "memory"); };

    // prologue: tile0 -> buf0, tile1 -> buf1 (8 half-tile stages = 16 loads)
    stgA(0, 0, 0); stgA(0, 1, 0); stgB(0, 0, 0); stgB(0, 1, 0);
    stgA(1, 0, 1); stgA(1, 1, 1); stgB(1, 0, 1); stgB(1, 1, 1);
    vm8();                                    // oldest 8 loads done = buf0 landed
    bar();

#pragma unroll 1
    for (int i = 0; i < NT / 2; ++i) {
        const int t2 = (2 * i + 2) & (NT - 1);   // wrap keeps tail stages in-bounds
        const int t3 = (2 * i + 3) & (NT - 1);   // (wrapped values never consumed)
        // ---- tile 2i from buf0 ----
        rdA(0, 0); rdB(0, 0);                                 // ph1
        bar(); lgkm0(); mm(0, 0); bar();
        rdB(1, 0);                                            // ph2
        bar(); lgkm0(); mm(0, 1); bar();
        rdA(1, 0); stgB(0, 0, t2);                            // ph3 (B-buf0 free)
        bar(); lgkm0(); mm(1, 1); bar();
        stgB(0, 1, t2); vm4();                                // ph4: buf1 landed
        bar(); mm(1, 0); bar();
        // ---- tile 2i+1 from buf1 ----
        rdA(0, 1); rdB(0, 1); stgA(0, 0, t2);                 // ph5 (A-buf0 free)
        bar(); lgkm0(); mm(0, 0); bar();
        rdB(1, 1); stgA(0, 1, t2);                            // ph6
        bar(); lgkm0(); mm(0, 1); bar();
        rdA(1, 1); stgB(1, 0, t3);                            // ph7 (B-buf1 free)
        bar(); lgkm0(); mm(1, 1); bar();
        stgB(1, 1, t3); stgA(1, 0, t3); stgA(1, 1, t3);       // ph8 (A-buf1 free)
        vm8();                                 // all but 4 newest done = buf0 landed
        bar(); mm(1, 0); bar();
    }
    // drain trailing (wrapped) stages before epilogue / LDS dealloc
    asm volatile("s_waitcnt vmcnt(0)" ::: "memory");
}

// ---------------------------------------------------------------------------
// QKV GEMM: C[16384 x 3072] = xh[16384x1024] @ [Wq|Wk|Wv]^T(as [N][K]) + bias
// ---------------------------------------------------------------------------
__global__ __launch_bounds__(512, 2)
void gemm_qkv8(const unsigned short* __restrict__ X, const unsigned short* __restrict__ Wt,
               const float* __restrict__ bq, const float* __restrict__ bk,
               const float* __restrict__ bv,
               _Float16* __restrict__ Qh, _Float16* __restrict__ Kh,
               unsigned short* __restrict__ Vt)
{
    extern __shared__ unsigned short smem[];
    unsigned short* sA = smem;
    unsigned short* sB = smem + 32768;

    constexpr int GX = 12, GY = 64, NWG = GX * GY;            // 768 % 8 == 0
    const int d = blockIdx.y * GX + blockIdx.x;
    const int wf = (d & 7) * (NWG >> 3) + (d >> 3);           // XCD-chunked swizzle
    const int bx = wf % GX, by = wf / GX;

    const long m0 = (long)by * 256;
    const int n0 = bx * 256;

    floatx4 acc[8][4] = {};
    gemm_core8<1024, 1024, 16, false>(X + m0 * 1024, Wt + (long)n0 * 1024, sA, sB, acc);

    const int tid = threadIdx.x;
    const int lane = tid & 63, quad = lane >> 4, l15 = lane & 15;
    const int wave = tid >> 6, wm = wave >> 2, wn = wave & 3;

    const int which = n0 >> 10;                               // 0=Q 1=K 2=V
    const int ncol0 = n0 & 1023;
    const float* bias = (which == 0) ? bq : (which == 1) ? bk : bv;

    if (which < 2) {
        _Float16* O = which ? Kh : Qh;
#pragma unroll
        for (int i = 0; i < 8; ++i) {
            const long mb = m0 + wm * 128 + i * 16 + quad * 4;
#pragma unroll
            for (int j = 0; j < 4; ++j) {
                const int col = ncol0 + wn * 64 + j * 16 + l15;
                const float bb = bias[col];
                _Float16* op = O + mb * 1024 + col;
#pragma unroll
                for (int r = 0; r < 4; ++r)
                    op[(long)r * 1024] = (_Float16)(acc[i][j][r] + bb);
            }
        }
    } else {
#pragma unroll
        for (int i = 0; i < 8; ++i) {
            const long mb = m0 + wm * 128 + i * 16 + quad * 4;
            const int bz = (int)(mb >> 11);
            const int s = (int)(mb & 2047);
#pragma unroll
            for (int j = 0; j < 4; ++j) {
                const int col = ncol0 + wn * 64 + j * 16 + l15;
                const float bb = bias[col];
                ushort4v h;
#pragma unroll
                for (int r = 0; r < 4; ++r) h[r] = f2bf(acc[i][j][r] + bb);
                *(ushort4v*)(Vt + (long)bz * 2097152 + (long)col * 2048 + s) = h;
            }
        }
    }
}

// ---------------------------------------------------------------------------
// Scores GEMM + fused exp/rowsum: E[z][m][n] = exp(Q_m . K_n - 40)  (bf16)
// ---------------------------------------------------------------------------
__global__ __launch_bounds__(512, 2)
void gemm_sc8(const unsigned short* __restrict__ Q, const unsigned short* __restrict__ K,
              unsigned short* __restrict__ E, float* __restrict__ rowsum)
{
    extern __shared__ unsigned short smem[];
    unsigned short* sA = smem;
    unsigned short* sB = smem + 32768;

    constexpr int GX = 8, GY = 8, NWG = GX * GY;              // 64 % 8 == 0
    const int d = blockIdx.y * GX + blockIdx.x;
    const int wf = (d & 7) * (NWG >> 3) + (d >> 3);
    const int bx = wf % GX, by = wf / GX;

    const long m0 = (long)by * 256;
    const long n0 = (long)bx * 256;
    const long zo = (long)blockIdx.z * 2097152;
    unsigned short* Eb = E + (long)blockIdx.z * 4194304;
    float* rs = rowsum + (long)blockIdx.z * 2048;

    floatx4 acc[8][4] = {};
    gemm_core8<1024, 1024, 16, false>(Q + zo + m0 * 1024, K + zo + n0 * 1024, sA, sB, acc);

    const int tid = threadIdx.x;
    const int lane = tid & 63, quad = lane >> 4, l15 = lane & 15;
    const int wave = tid >> 6, wm = wave >> 2, wn = wave & 3;

#pragma unroll
    for (int i = 0; i < 8; ++i) {
        const int rowb = (int)m0 + wm * 128 + i * 16 + quad * 4;
#pragma unroll
        for (int r = 0; r < 4; ++r) {
            float sl = 0.f;
#pragma unroll
            for (int j = 0; j < 4; ++j) {
                const long col = n0 + wn * 64 + j * 16 + l15;
                const unsigned short bb = f2bf(__expf(acc[i][j][r] - 40.0f));
                Eb[(long)(rowb + r) * 2048 + col] = bb;
                sl += bf2f(bb);           // sum the ROUNDED value (matches PV input)
            }
            sl += __shfl_xor(sl, 1);
            sl += __shfl_xor(sl, 2);
            sl += __shfl_xor(sl, 4);
            sl += __shfl_xor(sl, 8);      // sum over the 16-lane l15 group
            if (l15 == 0) atomicAdd(&rs[rowb + r], sl);
        }
    }
}

// ---------------------------------------------------------------------------
// Context GEMM (bf16): out[z][m][d] = (sum_k E[m][k] * Vt[d][k]) / rowsum[z][m]
// ---------------------------------------------------------------------------
__global__ __launch_bounds__(512, 2)
void gemm_pv8(const unsigned short* __restrict__ E, const unsigned short* __restrict__ Vt,
              const float* __restrict__ rowsum, float* __restrict__ C)
{
    extern __shared__ unsigned short smem[];
    unsigned short* sA = smem;
    unsigned short* sB = smem + 32768;

    constexpr int GX = 4, GY = 8, NWG = GX * GY;              // 32 % 8 == 0
    const int d = blockIdx.y * GX + blockIdx.x;
    const int wf = (d & 7) * (NWG >> 3) + (d >> 3);
    const int bx = wf % GX, by = wf / GX;

    const long m0 = (long)by * 256;
    const long n0 = (long)bx * 256;

    const unsigned short* Ab = E + (long)blockIdx.z * 4194304 + m0 * 2048;
    const unsigned short* Bb = Vt + (long)blockIdx.z * 2097152 + n0 * 2048;
    const float* rs = rowsum + (long)blockIdx.z * 2048;
    float* Cb = C + (long)blockIdx.z * 2097152;

    floatx4 acc[8][4] = {};
    gemm_core8<2048, 2048, 32, true>(Ab, Bb, sA, sB, acc);

    const int tid = threadIdx.x;
    const int lane = tid & 63, quad = lane >> 4, l15 = lane & 15;
    const int wave = tid >> 6, wm = wave >> 2, wn = wave & 3;

#pragma unroll
    for (int i = 0; i < 8; ++i) {
        const int rowb = (int)m0 + wm * 128 + i * 16 + quad * 4;
#pragma unroll
        for (int r = 0; r < 4; ++r) {
            const float inv = 1.0f / rs[rowb + r];
            float* cp = Cb + (long)(rowb + r) * 1024 + n0 + wn * 64 + l15;
#pragma unroll
            for (int j = 0; j < 4; ++j)
                cp[j * 16] = acc[i][j][r] * inv;
        }
    }
}

// ---------------------------------------------------------------------------
extern "C" void kernel_launch(void* const* d_in, const int* in_sizes, int n_in,
                              void* d_out, int out_size, void* d_ws, size_t ws_size,
                              hipStream_t stream)
{
    const float* x  = (const float*)d_in[0];
    const float* Wq = (const float*)d_in[1];
    const float* bq = (const float*)d_in[2];
    const float* Wk = (const float*)d_in[3];
    const float* bk = (const float*)d_in[4];
    const float* Wv = (const float*)d_in[5];
    const float* bv = (const float*)d_in[6];
    float* out = (float*)d_out;

    char* ws = (char*)d_ws;
    _Float16* Qh = (_Float16*)ws;              // [16384][1024] fp16
    _Float16* Kh = Qh + 16777216;              // [16384][1024] fp16
    unsigned short* Vt = (unsigned short*)(Kh + 16777216);  // 8 x [1024][2048] bf16
    char* region = ws + 100663296;             // (xh+Wt) then E
    _Float16* xh = (_Float16*)region;          // [16384][1024] fp16 (dead after QKV)
    _Float16* Wt = xh + 16777216;              // [3072][1024] fp16  (dead after QKV)
    unsigned short* E = (unsigned short*)region;  // c x [2048][2048] bf16

    // chunk c: region = max(xh+Wt = 39845888, c*8388608); + rowsum 64KB
    int c = 8;
    size_t region_sz;
    for (;;) {
        region_sz = (size_t)c * 8388608ull;
        if (region_sz < 39845888ull) region_sz = 39845888ull;
        if (100663296ull + region_sz + 65536ull <= ws_size || c == 1) break;
        c >>= 1;
    }
    float* rowsum = (float*)(ws + 100663296 + region_sz);   // c x 2048 fp32

    static bool attr_done = false;
    if (!attr_done) {
        hipFuncSetAttribute((const void*)gemm_qkv8,
                            hipFuncAttributeMaxDynamicSharedMemorySize, 131072);
        hipFuncSetAttribute((const void*)gemm_sc8,
                            hipFuncAttributeMaxDynamicSharedMemorySize, 131072);
        hipFuncSetAttribute((const void*)gemm_pv8,
                            hipFuncAttributeMaxDynamicSharedMemorySize, 131072);
        attr_done = true;
    }

    cvt_f2h<<<2048, 256, 0, stream>>>(x, xh, 16777216 / 4);
    transpose_w<<<dim3(32, 32, 3), dim3(32, 8, 1), 0, stream>>>(Wq, Wk, Wv, Wt);
    gemm_qkv8<<<dim3(12, 64, 1), 512, 131072, stream>>>(
        (const unsigned short*)xh, (const unsigned short*)Wt, bq, bk, bv, Qh, Kh, Vt);

    for (int b0 = 0; b0 < 8; b0 += c) {
        int cc = (8 - b0 < c) ? (8 - b0) : c;
        hipMemsetAsync(rowsum, 0, (size_t)cc * 2048 * 4, stream);
        gemm_sc8<<<dim3(8, 8, cc), 512, 131072, stream>>>(
            (const unsigned short*)(Qh + (long)b0 * 2097152),
            (const unsigned short*)(Kh + (long)b0 * 2097152), E, rowsum);
        gemm_pv8<<<dim3(4, 8, cc), 512, 131072, stream>>>(
            E, Vt + (long)b0 * 2097152, rowsum, out + (long)b0 * 2097152);
    }
}

// Round 3
// 387.822 us; speedup vs baseline: 1.0628x; 1.0059x over previous
//
#include <hip/hip_runtime.h>

typedef _Float16 half8 __attribute__((ext_vector_type(8)));
typedef _Float16 half4 __attribute__((ext_vector_type(4)));
typedef short short8 __attribute__((ext_vector_type(8)));
typedef unsigned short ushort4v __attribute__((ext_vector_type(4)));
typedef float floatx4 __attribute__((ext_vector_type(4)));

#define ASYNC16(g, l) __builtin_amdgcn_global_load_lds( \
    (const __attribute__((address_space(1))) void*)(g),  \
    (__attribute__((address_space(3))) void*)(l), 16, 0, 0)

__device__ inline unsigned short f2bf(float f) {          // RNE fp32->bf16
    unsigned u = __builtin_bit_cast(unsigned, f);
    u += 0x7fff + ((u >> 16) & 1);
    return (unsigned short)(u >> 16);
}
__device__ inline float bf2f(unsigned short b) {
    unsigned u = (unsigned)b << 16;
    return __builtin_bit_cast(float, u);
}

// ---------------------------------------------------------------------------
// fp32 -> fp16 bulk convert (vectorized, grid-stride)
// ---------------------------------------------------------------------------
__global__ void cvt_f2h(const float* __restrict__ in, _Float16* __restrict__ out, int n4)
{
    int i = blockIdx.x * blockDim.x + threadIdx.x;
    const int stride = gridDim.x * blockDim.x;
    for (; i < n4; i += stride) {
        float4 v = ((const float4*)in)[i];
        half4 h = { (_Float16)v.x, (_Float16)v.y, (_Float16)v.z, (_Float16)v.w };
        ((half4*)out)[i] = h;
    }
}

// ---------------------------------------------------------------------------
// W [K=1024][N=1024] fp32  ->  Wt [N][K] fp16   (z = which of Wq/Wk/Wv)
// ---------------------------------------------------------------------------
__global__ void transpose_w(const float* __restrict__ Wq, const float* __restrict__ Wk,
                            const float* __restrict__ Wv, _Float16* __restrict__ Wt)
{
    const float* W = (blockIdx.z == 0) ? Wq : (blockIdx.z == 1) ? Wk : Wv;
    _Float16* out = Wt + (size_t)blockIdx.z * 1024 * 1024;
    __shared__ float t[32][33];
    const int tx = threadIdx.x, ty = threadIdx.y;     // (32,8)
    const int k0 = blockIdx.x * 32, n0 = blockIdx.y * 32;
#pragma unroll
    for (int i = 0; i < 32; i += 8)
        t[ty + i][tx] = W[(size_t)(k0 + ty + i) * 1024 + n0 + tx];   // t[k][n]
    __syncthreads();
#pragma unroll
    for (int i = 0; i < 32; i += 8)
        out[(size_t)(n0 + ty + i) * 1024 + k0 + tx] = (_Float16)t[tx][ty + i];  // out[n][k]=W[k][n]
}

// ---------------------------------------------------------------------------
// 256x256 8-phase counted-vmcnt GEMM core (T3+T4+T5), BK=64, 512 threads.
// R3: removed sched_barrier(0) (it pinned reads before MFMAs -> coarse split,
//     m141/m196 failure mode); stages smoothed to 1 half-tile per phase.
// Stage ledger (write-after-last-read / land-before-read, all gated vm4):
//   ph1: buf1.Ah0(t1)  ph2: buf1.Ah1(t1)   [buf1.A last read prev ph7]
//   ph3: buf0.Bh0(t2)  ph4: buf0.Bh1(t2)+vm4  [buf0.B last read ph2]
//   ph5: buf0.Ah0(t2)  ph6: buf0.Ah1(t2)   [buf0.A last read ph3]
//   ph7: buf1.Bh0(t3)  ph8: buf1.Bh1(t3)+vm4  [buf1.B last read ph6]
//   vm4 @ph4: all but 2 newest stages landed -> buf1 (prev7,prev8,ph1,ph2) ready
//   vm4 @ph8: all but 2 newest landed -> buf0 (ph3..ph6) ready for next ph1
// ---------------------------------------------------------------------------
template<bool BF16>
__device__ __forceinline__ floatx4 MF(short8 a, short8 b, floatx4 c) {
    if constexpr (BF16)
        return __builtin_amdgcn_mfma_f32_16x16x32_bf16(a, b, c, 0, 0, 0);
    else
        return __builtin_amdgcn_mfma_f32_16x16x32_f16(
            __builtin_bit_cast(half8, a), __builtin_bit_cast(half8, b), c, 0, 0, 0);
}

template<int LDA, int LDB, int NT, bool BF16>
__device__ __forceinline__ void gemm_core8(
    const unsigned short* __restrict__ Ab, const unsigned short* __restrict__ Bb,
    unsigned short* sA, unsigned short* sB, floatx4 (&acc)[8][4])
{
    const int tid = threadIdx.x;
    const int lane = tid & 63, quad = lane >> 4, l15 = lane & 15;
    const int wave = tid >> 6;
    const int wm = wave >> 2, wn = wave & 3;
    const int rowbase = wm * 128, colbase = wn * 64;
    const int sw = l15 & 7;

    long srcA[2], srcB[2];
    int dst[2];
#pragma unroll
    for (int u = 0; u < 2; ++u) {
        const int c = tid + u * 512;
        const int row = c >> 3;                 // row within 128-row half
        const int g = (c & 7) ^ (row & 7);      // pre-swizzled global chunk
        srcA[u] = (long)row * LDA + g * 8;
        srcB[u] = (long)row * LDB + g * 8;
        dst[u] = c * 16;                        // linear LDS bytes within half
    }

    short8 a[4][2], b[2][2][2];

    auto stgA = [&](int p, int h, int kt) {
#pragma unroll
        for (int u = 0; u < 2; ++u)
            ASYNC16(Ab + (long)kt * 64 + (long)h * (128 * LDA) + srcA[u],
                    (char*)sA + p * 32768 + h * 16384 + dst[u]);
    };
    auto stgB = [&](int p, int h, int kt) {
#pragma unroll
        for (int u = 0; u < 2; ++u)
            ASYNC16(Bb + (long)kt * 64 + (long)h * (128 * LDB) + srcB[u],
                    (char*)sB + p * 32768 + h * 16384 + dst[u]);
    };
    auto rdA = [&](int mq, int p) {
#pragma unroll
        for (int ii = 0; ii < 4; ++ii) {
            const int row = rowbase + (mq * 4 + ii) * 16 + l15;
#pragma unroll
            for (int kk = 0; kk < 2; ++kk)
                a[ii][kk] = *(const short8*)(sA + p * 16384 + row * 64 +
                                             (((kk * 4 + quad) ^ sw) * 8));
        }
    };
    auto rdB = [&](int nq, int p) {
#pragma unroll
        for (int jj = 0; jj < 2; ++jj) {
            const int row = colbase + (nq * 2 + jj) * 16 + l15;
#pragma unroll
            for (int kk = 0; kk < 2; ++kk)
                b[nq][jj][kk] = *(const short8*)(sB + p * 16384 + row * 64 +
                                                 (((kk * 4 + quad) ^ sw) * 8));
        }
    };
    auto mm = [&](int mq, int nq) {
        __builtin_amdgcn_s_setprio(1);
#pragma unroll
        for (int ii = 0; ii < 4; ++ii)
#pragma unroll
            for (int jj = 0; jj < 2; ++jj)
#pragma unroll
                for (int kk = 0; kk < 2; ++kk)
                    acc[mq * 4 + ii][nq * 2 + jj] =
                        MF<BF16>(a[ii][kk], b[nq][jj][kk], acc[mq * 4 + ii][nq * 2 + jj]);
        __builtin_amdgcn_s_setprio(0);
    };
    auto bar   = [] { __builtin_amdgcn_s_barrier(); };
    // NOTE: no sched_barrier here — ds_reads are compiler-visible; pinning them
    // before the MFMAs (R2) destroyed the fine interleave (m141/m196).
    auto lgkm0 = [] { asm volatile("s_waitcnt lgkmcnt(0)" ::: "memory"); };
    auto hint8 = [] { asm volatile("s_waitcnt lgkmcnt(8)" ::: "memory"); };
    auto vm4   = [] { asm volatile("s_waitcnt vmcnt(4)" ::: "memory"); };

    // prologue: buf0 <- tile0 (4 half-tiles), buf1.B <- tile1 (2 half-tiles)
    stgA(0, 0, 0); stgA(0, 1, 0); stgB(0, 0, 0); stgB(0, 1, 0);
    stgB(1, 0, 1); stgB(1, 1, 1);
    vm4();                                    // all but 2 newest done = buf0 landed
    bar();

#pragma unroll 1
    for (int i = 0; i < NT / 2; ++i) {
        const int t1 = 2 * i + 1;
        const int t2 = (2 * i + 2) & (NT - 1);   // wrap keeps tail stages in-bounds
        const int t3 = (2 * i + 3) & (NT - 1);   // (wrapped values never consumed)
        // ---- tile 2i from buf0 ----
        rdA(0, 0); rdB(0, 0); stgA(1, 0, t1); hint8();        // ph1
        bar(); lgkm0(); mm(0, 0); bar();
        rdB(1, 0); stgA(1, 1, t1);                            // ph2
        bar(); lgkm0(); mm(0, 1); bar();
        rdA(1, 0); stgB(0, 0, t2);                            // ph3
        bar(); lgkm0(); mm(1, 1); bar();
        stgB(0, 1, t2); vm4();                                // ph4: buf1 landed
        bar(); mm(1, 0); bar();
        // ---- tile 2i+1 from buf1 ----
        rdA(0, 1); rdB(0, 1); stgA(0, 0, t2); hint8();        // ph5
        bar(); lgkm0(); mm(0, 0); bar();
        rdB(1, 1); stgA(0, 1, t2);                            // ph6
        bar(); lgkm0(); mm(0, 1); bar();
        rdA(1, 1); stgB(1, 0, t3);                            // ph7
        bar(); lgkm0(); mm(1, 1); bar();
        stgB(1, 1, t3); vm4();                                // ph8: buf0 landed
        bar(); mm(1, 0); bar();
    }
    // drain trailing (wrapped) stages before epilogue / LDS dealloc
    asm volatile("s_waitcnt vmcnt(0)" ::: "memory");
}

// ---------------------------------------------------------------------------
// QKV GEMM: C[16384 x 3072] = xh[16384x1024] @ [Wq|Wk|Wv]^T(as [N][K]) + bias
// ---------------------------------------------------------------------------
__global__ __launch_bounds__(512, 2)
void gemm_qkv8(const unsigned short* __restrict__ X, const unsigned short* __restrict__ Wt,
               const float* __restrict__ bq, const float* __restrict__ bk,
               const float* __restrict__ bv,
               _Float16* __restrict__ Qh, _Float16* __restrict__ Kh,
               unsigned short* __restrict__ Vt)
{
    extern __shared__ unsigned short smem[];
    unsigned short* sA = smem;
    unsigned short* sB = smem + 32768;

    constexpr int GX = 12, GY = 64, NWG = GX * GY;            // 768 % 8 == 0
    const int d = blockIdx.y * GX + blockIdx.x;
    const int wf = (d & 7) * (NWG >> 3) + (d >> 3);           // XCD-chunked swizzle
    const int bx = wf % GX, by = wf / GX;

    const long m0 = (long)by * 256;
    const int n0 = bx * 256;

    floatx4 acc[8][4] = {};
    gemm_core8<1024, 1024, 16, false>(X + m0 * 1024, Wt + (long)n0 * 1024, sA, sB, acc);

    const int tid = threadIdx.x;
    const int lane = tid & 63, quad = lane >> 4, l15 = lane & 15;
    const int wave = tid >> 6, wm = wave >> 2, wn = wave & 3;

    const int which = n0 >> 10;                               // 0=Q 1=K 2=V
    const int ncol0 = n0 & 1023;
    const float* bias = (which == 0) ? bq : (which == 1) ? bk : bv;

    if (which < 2) {
        _Float16* O = which ? Kh : Qh;
#pragma unroll
        for (int i = 0; i < 8; ++i) {
            const long mb = m0 + wm * 128 + i * 16 + quad * 4;
#pragma unroll
            for (int j = 0; j < 4; ++j) {
                const int col = ncol0 + wn * 64 + j * 16 + l15;
                const float bb = bias[col];
                _Float16* op = O + mb * 1024 + col;
#pragma unroll
                for (int r = 0; r < 4; ++r)
                    op[(long)r * 1024] = (_Float16)(acc[i][j][r] + bb);
            }
        }
    } else {
#pragma unroll
        for (int i = 0; i < 8; ++i) {
            const long mb = m0 + wm * 128 + i * 16 + quad * 4;
            const int bz = (int)(mb >> 11);
            const int s = (int)(mb & 2047);
#pragma unroll
            for (int j = 0; j < 4; ++j) {
                const int col = ncol0 + wn * 64 + j * 16 + l15;
                const float bb = bias[col];
                ushort4v h;
#pragma unroll
                for (int r = 0; r < 4; ++r) h[r] = f2bf(acc[i][j][r] + bb);
                *(ushort4v*)(Vt + (long)bz * 2097152 + (long)col * 2048 + s) = h;
            }
        }
    }
}

// ---------------------------------------------------------------------------
// Scores GEMM + fused exp/rowsum: E[z][m][n] = exp(Q_m . K_n - 40)  (bf16)
// ---------------------------------------------------------------------------
__global__ __launch_bounds__(512, 2)
void gemm_sc8(const unsigned short* __restrict__ Q, const unsigned short* __restrict__ K,
              unsigned short* __restrict__ E, float* __restrict__ rowsum)
{
    extern __shared__ unsigned short smem[];
    unsigned short* sA = smem;
    unsigned short* sB = smem + 32768;

    constexpr int GX = 8, GY = 8, NWG = GX * GY;              // 64 % 8 == 0
    const int d = blockIdx.y * GX + blockIdx.x;
    const int wf = (d & 7) * (NWG >> 3) + (d >> 3);
    const int bx = wf % GX, by = wf / GX;

    const long m0 = (long)by * 256;
    const long n0 = (long)bx * 256;
    const long zo = (long)blockIdx.z * 2097152;
    unsigned short* Eb = E + (long)blockIdx.z * 4194304;
    float* rs = rowsum + (long)blockIdx.z * 2048;

    floatx4 acc[8][4] = {};
    gemm_core8<1024, 1024, 16, false>(Q + zo + m0 * 1024, K + zo + n0 * 1024, sA, sB, acc);

    const int tid = threadIdx.x;
    const int lane = tid & 63, quad = lane >> 4, l15 = lane & 15;
    const int wave = tid >> 6, wm = wave >> 2, wn = wave & 3;

#pragma unroll
    for (int i = 0; i < 8; ++i) {
        const int rowb = (int)m0 + wm * 128 + i * 16 + quad * 4;
#pragma unroll
        for (int r = 0; r < 4; ++r) {
            float sl = 0.f;
#pragma unroll
            for (int j = 0; j < 4; ++j) {
                const long col = n0 + wn * 64 + j * 16 + l15;
                const unsigned short bb = f2bf(__expf(acc[i][j][r] - 40.0f));
                Eb[(long)(rowb + r) * 2048 + col] = bb;
                sl += bf2f(bb);           // sum the ROUNDED value (matches PV input)
            }
            sl += __shfl_xor(sl, 1);
            sl += __shfl_xor(sl, 2);
            sl += __shfl_xor(sl, 4);
            sl += __shfl_xor(sl, 8);      // sum over the 16-lane l15 group
            if (l15 == 0) atomicAdd(&rs[rowb + r], sl);
        }
    }
}

// ---------------------------------------------------------------------------
// Context GEMM (bf16): out[z][m][d] = (sum_k E[m][k] * Vt[d][k]) / rowsum[z][m]
// ---------------------------------------------------------------------------
__global__ __launch_bounds__(512, 2)
void gemm_pv8(const unsigned short* __restrict__ E, const unsigned short* __restrict__ Vt,
              const float* __restrict__ rowsum, float* __restrict__ C)
{
    extern __shared__ unsigned short smem[];
    unsigned short* sA = smem;
    unsigned short* sB = smem + 32768;

    constexpr int GX = 4, GY = 8, NWG = GX * GY;              // 32 % 8 == 0
    const int d = blockIdx.y * GX + blockIdx.x;
    const int wf = (d & 7) * (NWG >> 3) + (d >> 3);
    const int bx = wf % GX, by = wf / GX;

    const long m0 = (long)by * 256;
    const long n0 = (long)bx * 256;

    const unsigned short* Ab = E + (long)blockIdx.z * 4194304 + m0 * 2048;
    const unsigned short* Bb = Vt + (long)blockIdx.z * 2097152 + n0 * 2048;
    const float* rs = rowsum + (long)blockIdx.z * 2048;
    float* Cb = C + (long)blockIdx.z * 2097152;

    floatx4 acc[8][4] = {};
    gemm_core8<2048, 2048, 32, true>(Ab, Bb, sA, sB, acc);

    const int tid = threadIdx.x;
    const int lane = tid & 63, quad = lane >> 4, l15 = lane & 15;
    const int wave = tid >> 6, wm = wave >> 2, wn = wave & 3;

#pragma unroll
    for (int i = 0; i < 8; ++i) {
        const int rowb = (int)m0 + wm * 128 + i * 16 + quad * 4;
#pragma unroll
        for (int r = 0; r < 4; ++r) {
            const float inv = 1.0f / rs[rowb + r];
            float* cp = Cb + (long)(rowb + r) * 1024 + n0 + wn * 64 + l15;
#pragma unroll
            for (int j = 0; j < 4; ++j)
                cp[j * 16] = acc[i][j][r] * inv;
        }
    }
}

// ---------------------------------------------------------------------------
extern "C" void kernel_launch(void* const* d_in, const int* in_sizes, int n_in,
                              void* d_out, int out_size, void* d_ws, size_t ws_size,
                              hipStream_t stream)
{
    const float* x  = (const float*)d_in[0];
    const float* Wq = (const float*)d_in[1];
    const float* bq = (const float*)d_in[2];
    const float* Wk = (const float*)d_in[3];
    const float* bk = (const float*)d_in[4];
    const float* Wv = (const float*)d_in[5];
    const float* bv = (const float*)d_in[6];
    float* out = (float*)d_out;

    char* ws = (char*)d_ws;
    _Float16* Qh = (_Float16*)ws;              // [16384][1024] fp16
    _Float16* Kh = Qh + 16777216;              // [16384][1024] fp16
    unsigned short* Vt = (unsigned short*)(Kh + 16777216);  // 8 x [1024][2048] bf16
    char* region = ws + 100663296;             // (xh+Wt) then E
    _Float16* xh = (_Float16*)region;          // [16384][1024] fp16 (dead after QKV)
    _Float16* Wt = xh + 16777216;              // [3072][1024] fp16  (dead after QKV)
    unsigned short* E = (unsigned short*)region;  // c x [2048][2048] bf16

    // chunk c: region = max(xh+Wt = 39845888, c*8388608); + rowsum 64KB
    int c = 8;
    size_t region_sz;
    for (;;) {
        region_sz = (size_t)c * 8388608ull;
        if (region_sz < 39845888ull) region_sz = 39845888ull;
        if (100663296ull + region_sz + 65536ull <= ws_size || c == 1) break;
        c >>= 1;
    }
    float* rowsum = (float*)(ws + 100663296 + region_sz);   // c x 2048 fp32

    static bool attr_done = false;
    if (!attr_done) {
        hipFuncSetAttribute((const void*)gemm_qkv8,
                            hipFuncAttributeMaxDynamicSharedMemorySize, 131072);
        hipFuncSetAttribute((const void*)gemm_sc8,
                            hipFuncAttributeMaxDynamicSharedMemorySize, 131072);
        hipFuncSetAttribute((const void*)gemm_pv8,
                            hipFuncAttributeMaxDynamicSharedMemorySize, 131072);
        attr_done = true;
    }

    cvt_f2h<<<2048, 256, 0, stream>>>(x, xh, 16777216 / 4);
    transpose_w<<<dim3(32, 32, 3), dim3(32, 8, 1), 0, stream>>>(Wq, Wk, Wv, Wt);
    gemm_qkv8<<<dim3(12, 64, 1), 512, 131072, stream>>>(
        (const unsigned short*)xh, (const unsigned short*)Wt, bq, bk, bv, Qh, Kh, Vt);

    for (int b0 = 0; b0 < 8; b0 += c) {
        int cc = (8 - b0 < c) ? (8 - b0) : c;
        hipMemsetAsync(rowsum, 0, (size_t)cc * 2048 * 4, stream);
        gemm_sc8<<<dim3(8, 8, cc), 512, 131072, stream>>>(
            (const unsigned short*)(Qh + (long)b0 * 2097152),
            (const unsigned short*)(Kh + (long)b0 * 2097152), E, rowsum);
        gemm_pv8<<<dim3(4, 8, cc), 512, 131072, stream>>>(
            E, Vt + (long)b0 * 2097152, rowsum, out + (long)b0 * 2097152);
    }
}

// Round 4
// 384.713 us; speedup vs baseline: 1.0714x; 1.0081x over previous
//
#include <hip/hip_runtime.h>

typedef _Float16 half8 __attribute__((ext_vector_type(8)));
typedef _Float16 half4 __attribute__((ext_vector_type(4)));
typedef short short8 __attribute__((ext_vector_type(8)));
typedef unsigned short ushort4v __attribute__((ext_vector_type(4)));
typedef float floatx4 __attribute__((ext_vector_type(4)));

#define ASYNC16(g, l) __builtin_amdgcn_global_load_lds( \
    (const __attribute__((address_space(1))) void*)(g),  \
    (__attribute__((address_space(3))) void*)(l), 16, 0, 0)

__device__ inline unsigned short f2bf(float f) {          // RNE fp32->bf16
    unsigned u = __builtin_bit_cast(unsigned, f);
    u += 0x7fff + ((u >> 16) & 1);
    return (unsigned short)(u >> 16);
}
__device__ inline float bf2f(unsigned short b) {
    unsigned u = (unsigned)b << 16;
    return __builtin_bit_cast(float, u);
}

// ---------------------------------------------------------------------------
// fp32 -> fp16 bulk convert (vectorized, grid-stride)
// ---------------------------------------------------------------------------
__global__ void cvt_f2h(const float* __restrict__ in, _Float16* __restrict__ out, int n4)
{
    int i = blockIdx.x * blockDim.x + threadIdx.x;
    const int stride = gridDim.x * blockDim.x;
    for (; i < n4; i += stride) {
        float4 v = ((const float4*)in)[i];
        half4 h = { (_Float16)v.x, (_Float16)v.y, (_Float16)v.z, (_Float16)v.w };
        ((half4*)out)[i] = h;
    }
}

// ---------------------------------------------------------------------------
// W [K=1024][N=1024] fp32  ->  Wt [N][K] fp16   (z = which of Wq/Wk/Wv)
// ---------------------------------------------------------------------------
__global__ void transpose_w(const float* __restrict__ Wq, const float* __restrict__ Wk,
                            const float* __restrict__ Wv, _Float16* __restrict__ Wt)
{
    const float* W = (blockIdx.z == 0) ? Wq : (blockIdx.z == 1) ? Wk : Wv;
    _Float16* out = Wt + (size_t)blockIdx.z * 1024 * 1024;
    __shared__ float t[32][33];
    const int tx = threadIdx.x, ty = threadIdx.y;     // (32,8)
    const int k0 = blockIdx.x * 32, n0 = blockIdx.y * 32;
#pragma unroll
    for (int i = 0; i < 32; i += 8)
        t[ty + i][tx] = W[(size_t)(k0 + ty + i) * 1024 + n0 + tx];   // t[k][n]
    __syncthreads();
#pragma unroll
    for (int i = 0; i < 32; i += 8)
        out[(size_t)(n0 + ty + i) * 1024 + k0 + tx] = (_Float16)t[tx][ty + i];  // out[n][k]=W[k][n]
}

// ---------------------------------------------------------------------------
// 256x256 8-phase counted-vmcnt GEMM core, BK=64, 512 threads.
// R4: ds_reads for phase k+1 moved INTO phase k's MFMA region (overlap LDS
//     burst with MFMA instead of serializing before the barrier); ds addresses
//     collapsed to 4 base pointers + immediate offsets (kills VALU churn).
// Phase k = [stage 1 half-tile] BAR [lgkm0; prio1{16 MFMA; reads_{k+1}}prio0] BAR
// Stage ledger (same as R3):
//   ph1: buf1.Ah0(t1)  ph2: buf1.Ah1(t1)  ph3: buf0.Bh0(t2)  ph4: buf0.Bh1+vm4
//   ph5: buf0.Ah0(t2)  ph6: buf0.Ah1(t2)  ph7: buf1.Bh0(t3)  ph8: buf1.Bh1+vm4
// Read regions: ph8:{A0,B0 buf0} ph1:{B1 b0} ph2:{A1 b0} ph4:{A0,B0 buf1}
//               ph5:{B1 b1} ph6:{A1 b1}  — each after the vm4+BAR guarding it.
// ---------------------------------------------------------------------------
template<bool BF16>
__device__ __forceinline__ floatx4 MF(short8 a, short8 b, floatx4 c) {
    if constexpr (BF16)
        return __builtin_amdgcn_mfma_f32_16x16x32_bf16(a, b, c, 0, 0, 0);
    else
        return __builtin_amdgcn_mfma_f32_16x16x32_f16(
            __builtin_bit_cast(half8, a), __builtin_bit_cast(half8, b), c, 0, 0, 0);
}

template<int LDA, int LDB, int NT, bool BF16>
__device__ __forceinline__ void gemm_core8(
    const unsigned short* __restrict__ Ab, const unsigned short* __restrict__ Bb,
    unsigned short* sA, unsigned short* sB, floatx4 (&acc)[8][4])
{
    const int tid = threadIdx.x;
    const int lane = tid & 63, quad = lane >> 4, l15 = lane & 15;
    const int wave = tid >> 6;
    const int wm = wave >> 2, wn = wave & 3;
    const int rowbase = wm * 128, colbase = wn * 64;
    const int sw = l15 & 7;

    long srcA[2], srcB[2];
    int dst[2];
#pragma unroll
    for (int u = 0; u < 2; ++u) {
        const int c = tid + u * 512;
        const int row = c >> 3;                 // row within 128-row half
        const int g = (c & 7) ^ (row & 7);      // pre-swizzled global chunk
        srcA[u] = (long)row * LDA + g * 8;
        srcB[u] = (long)row * LDB + g * 8;
        dst[u] = c * 16;                        // linear LDS bytes within half
    }

    // Loop-invariant ds_read base pointers; everything else is an immediate:
    //   A frag (mq,ii,kk,p): aRd[kk] + p*32768 + mq*8192 + ii*2048
    //   B frag (nq,jj,kk,p): bRd[kk] + p*32768 + nq*4096 + jj*2048
    const char* aRd[2];
    const char* bRd[2];
#pragma unroll
    for (int kk = 0; kk < 2; ++kk) {
        const int ck = ((kk * 4 + quad) ^ sw) * 16;   // byte offset of k-chunk
        aRd[kk] = (const char*)sA + (rowbase + l15) * 128 + ck;
        bRd[kk] = (const char*)sB + (colbase + l15) * 128 + ck;
    }

    short8 a[4][2], b[2][2][2];

    auto stgA = [&](int p, int h, int kt) {
#pragma unroll
        for (int u = 0; u < 2; ++u)
            ASYNC16(Ab + (long)kt * 64 + (long)h * (128 * LDA) + srcA[u],
                    (char*)sA + p * 32768 + h * 16384 + dst[u]);
    };
    auto stgB = [&](int p, int h, int kt) {
#pragma unroll
        for (int u = 0; u < 2; ++u)
            ASYNC16(Bb + (long)kt * 64 + (long)h * (128 * LDB) + srcB[u],
                    (char*)sB + p * 32768 + h * 16384 + dst[u]);
    };
    auto rdA = [&](int mq, int p) {
#pragma unroll
        for (int ii = 0; ii < 4; ++ii)
#pragma unroll
            for (int kk = 0; kk < 2; ++kk)
                a[ii][kk] = *(const short8*)(aRd[kk] + p * 32768 + mq * 8192 + ii * 2048);
    };
    auto rdB = [&](int nq, int p) {
#pragma unroll
        for (int jj = 0; jj < 2; ++jj)
#pragma unroll
            for (int kk = 0; kk < 2; ++kk)
                b[nq][jj][kk] = *(const short8*)(bRd[kk] + p * 32768 + nq * 4096 + jj * 2048);
    };
    auto mm = [&](int mq, int nq) {
#pragma unroll
        for (int ii = 0; ii < 4; ++ii)
#pragma unroll
            for (int jj = 0; jj < 2; ++jj)
#pragma unroll
                for (int kk = 0; kk < 2; ++kk)
                    acc[mq * 4 + ii][nq * 2 + jj] =
                        MF<BF16>(a[ii][kk], b[nq][jj][kk], acc[mq * 4 + ii][nq * 2 + jj]);
    };
    auto bar   = [] { __builtin_amdgcn_s_barrier(); };
    auto lgkm0 = [] { asm volatile("s_waitcnt lgkmcnt(0)" ::: "memory"); };
    auto vm4   = [] { asm volatile("s_waitcnt vmcnt(4)" ::: "memory"); };
    auto pr1   = [] { __builtin_amdgcn_s_setprio(1); };
    auto pr0   = [] { __builtin_amdgcn_s_setprio(0); };

    // prologue: buf0 <- tile0 (4 half-tiles), buf1.B <- tile1 (2 half-tiles)
    stgA(0, 0, 0); stgA(0, 1, 0); stgB(0, 0, 0); stgB(0, 1, 0);
    stgB(1, 0, 1); stgB(1, 1, 1);
    vm4();                                    // all but 2 newest done = buf0 landed
    bar();
    rdA(0, 0); rdB(0, 0);                     // "ph8-region" reads for first ph1

#pragma unroll 1
    for (int i = 0; i < NT / 2; ++i) {
        const int t1 = 2 * i + 1;
        const int t2 = (2 * i + 2) & (NT - 1);   // wrap keeps tail stages in-bounds
        const int t3 = (2 * i + 3) & (NT - 1);   // (wrapped values never consumed)
        // ---- tile 2i from buf0 ----
        stgA(1, 0, t1);                                       // ph1
        bar(); lgkm0();
        pr1(); mm(0, 0); rdB(1, 0); pr0();
        bar();
        stgA(1, 1, t1);                                       // ph2
        bar(); lgkm0();
        pr1(); mm(0, 1); rdA(1, 0); pr0();
        bar();
        stgB(0, 0, t2);                                       // ph3
        bar(); lgkm0();
        pr1(); mm(1, 1); pr0();
        bar();
        stgB(0, 1, t2); vm4();                                // ph4: buf1 landed
        bar();
        pr1(); mm(1, 0); rdA(0, 1); rdB(0, 1); pr0();
        bar();
        // ---- tile 2i+1 from buf1 ----
        stgA(0, 0, t2);                                       // ph5
        bar(); lgkm0();
        pr1(); mm(0, 0); rdB(1, 1); pr0();
        bar();
        stgA(0, 1, t2);                                       // ph6
        bar(); lgkm0();
        pr1(); mm(0, 1); rdA(1, 1); pr0();
        bar();
        stgB(1, 0, t3);                                       // ph7
        bar(); lgkm0();
        pr1(); mm(1, 1); pr0();
        bar();
        stgB(1, 1, t3); vm4();                                // ph8: buf0 landed
        bar();
        pr1(); mm(1, 0); rdA(0, 0); rdB(0, 0); pr0();
        bar();
    }
    // drain trailing (wrapped) stages before epilogue / LDS dealloc
    asm volatile("s_waitcnt vmcnt(0)" ::: "memory");
}

// ---------------------------------------------------------------------------
// QKV GEMM: C[16384 x 3072] = xh[16384x1024] @ [Wq|Wk|Wv]^T(as [N][K]) + bias
// ---------------------------------------------------------------------------
__global__ __launch_bounds__(512, 2)
void gemm_qkv8(const unsigned short* __restrict__ X, const unsigned short* __restrict__ Wt,
               const float* __restrict__ bq, const float* __restrict__ bk,
               const float* __restrict__ bv,
               _Float16* __restrict__ Qh, _Float16* __restrict__ Kh,
               unsigned short* __restrict__ Vt)
{
    extern __shared__ unsigned short smem[];
    unsigned short* sA = smem;
    unsigned short* sB = smem + 32768;

    constexpr int GX = 12, GY = 64, NWG = GX * GY;            // 768 % 8 == 0
    const int d = blockIdx.y * GX + blockIdx.x;
    const int wf = (d & 7) * (NWG >> 3) + (d >> 3);           // XCD-chunked swizzle
    const int bx = wf % GX, by = wf / GX;

    const long m0 = (long)by * 256;
    const int n0 = bx * 256;

    floatx4 acc[8][4] = {};
    gemm_core8<1024, 1024, 16, false>(X + m0 * 1024, Wt + (long)n0 * 1024, sA, sB, acc);

    const int tid = threadIdx.x;
    const int lane = tid & 63, quad = lane >> 4, l15 = lane & 15;
    const int wave = tid >> 6, wm = wave >> 2, wn = wave & 3;

    const int which = n0 >> 10;                               // 0=Q 1=K 2=V
    const int ncol0 = n0 & 1023;
    const float* bias = (which == 0) ? bq : (which == 1) ? bk : bv;

    if (which < 2) {
        _Float16* O = which ? Kh : Qh;
#pragma unroll
        for (int i = 0; i < 8; ++i) {
            const long mb = m0 + wm * 128 + i * 16 + quad * 4;
#pragma unroll
            for (int j = 0; j < 4; ++j) {
                const int col = ncol0 + wn * 64 + j * 16 + l15;
                const float bb = bias[col];
                _Float16* op = O + mb * 1024 + col;
#pragma unroll
                for (int r = 0; r < 4; ++r)
                    op[(long)r * 1024] = (_Float16)(acc[i][j][r] + bb);
            }
        }
    } else {
#pragma unroll
        for (int i = 0; i < 8; ++i) {
            const long mb = m0 + wm * 128 + i * 16 + quad * 4;
            const int bz = (int)(mb >> 11);
            const int s = (int)(mb & 2047);
#pragma unroll
            for (int j = 0; j < 4; ++j) {
                const int col = ncol0 + wn * 64 + j * 16 + l15;
                const float bb = bias[col];
                ushort4v h;
#pragma unroll
                for (int r = 0; r < 4; ++r) h[r] = f2bf(acc[i][j][r] + bb);
                *(ushort4v*)(Vt + (long)bz * 2097152 + (long)col * 2048 + s) = h;
            }
        }
    }
}

// ---------------------------------------------------------------------------
// Scores GEMM + fused exp/rowsum: E[z][m][n] = exp(Q_m . K_n - 40)  (bf16)
// ---------------------------------------------------------------------------
__global__ __launch_bounds__(512, 2)
void gemm_sc8(const unsigned short* __restrict__ Q, const unsigned short* __restrict__ K,
              unsigned short* __restrict__ E, float* __restrict__ rowsum)
{
    extern __shared__ unsigned short smem[];
    unsigned short* sA = smem;
    unsigned short* sB = smem + 32768;

    constexpr int GX = 8, GY = 8, NWG = GX * GY;              // 64 % 8 == 0
    const int d = blockIdx.y * GX + blockIdx.x;
    const int wf = (d & 7) * (NWG >> 3) + (d >> 3);
    const int bx = wf % GX, by = wf / GX;

    const long m0 = (long)by * 256;
    const long n0 = (long)bx * 256;
    const long zo = (long)blockIdx.z * 2097152;
    unsigned short* Eb = E + (long)blockIdx.z * 4194304;
    float* rs = rowsum + (long)blockIdx.z * 2048;

    floatx4 acc[8][4] = {};
    gemm_core8<1024, 1024, 16, false>(Q + zo + m0 * 1024, K + zo + n0 * 1024, sA, sB, acc);

    const int tid = threadIdx.x;
    const int lane = tid & 63, quad = lane >> 4, l15 = lane & 15;
    const int wave = tid >> 6, wm = wave >> 2, wn = wave & 3;

#pragma unroll
    for (int i = 0; i < 8; ++i) {
        const int rowb = (int)m0 + wm * 128 + i * 16 + quad * 4;
#pragma unroll
        for (int r = 0; r < 4; ++r) {
            float sl = 0.f;
#pragma unroll
            for (int j = 0; j < 4; ++j) {
                const long col = n0 + wn * 64 + j * 16 + l15;
                const unsigned short bb = f2bf(__expf(acc[i][j][r] - 40.0f));
                Eb[(long)(rowb + r) * 2048 + col] = bb;
                sl += bf2f(bb);           // sum the ROUNDED value (matches PV input)
            }
            sl += __shfl_xor(sl, 1);
            sl += __shfl_xor(sl, 2);
            sl += __shfl_xor(sl, 4);
            sl += __shfl_xor(sl, 8);      // sum over the 16-lane l15 group
            if (l15 == 0) atomicAdd(&rs[rowb + r], sl);
        }
    }
}

// ---------------------------------------------------------------------------
// Context GEMM (bf16): out[z][m][d] = (sum_k E[m][k] * Vt[d][k]) / rowsum[z][m]
// ---------------------------------------------------------------------------
__global__ __launch_bounds__(512, 2)
void gemm_pv8(const unsigned short* __restrict__ E, const unsigned short* __restrict__ Vt,
              const float* __restrict__ rowsum, float* __restrict__ C)
{
    extern __shared__ unsigned short smem[];
    unsigned short* sA = smem;
    unsigned short* sB = smem + 32768;

    constexpr int GX = 4, GY = 8, NWG = GX * GY;              // 32 % 8 == 0
    const int d = blockIdx.y * GX + blockIdx.x;
    const int wf = (d & 7) * (NWG >> 3) + (d >> 3);
    const int bx = wf % GX, by = wf / GX;

    const long m0 = (long)by * 256;
    const long n0 = (long)bx * 256;

    const unsigned short* Ab = E + (long)blockIdx.z * 4194304 + m0 * 2048;
    const unsigned short* Bb = Vt + (long)blockIdx.z * 2097152 + n0 * 2048;
    const float* rs = rowsum + (long)blockIdx.z * 2048;
    float* Cb = C + (long)blockIdx.z * 2097152;

    floatx4 acc[8][4] = {};
    gemm_core8<2048, 2048, 32, true>(Ab, Bb, sA, sB, acc);

    const int tid = threadIdx.x;
    const int lane = tid & 63, quad = lane >> 4, l15 = lane & 15;
    const int wave = tid >> 6, wm = wave >> 2, wn = wave & 3;

#pragma unroll
    for (int i = 0; i < 8; ++i) {
        const int rowb = (int)m0 + wm * 128 + i * 16 + quad * 4;
#pragma unroll
        for (int r = 0; r < 4; ++r) {
            const float inv = 1.0f / rs[rowb + r];
            float* cp = Cb + (long)(rowb + r) * 1024 + n0 + wn * 64 + l15;
#pragma unroll
            for (int j = 0; j < 4; ++j)
                cp[j * 16] = acc[i][j][r] * inv;
        }
    }
}

// ---------------------------------------------------------------------------
extern "C" void kernel_launch(void* const* d_in, const int* in_sizes, int n_in,
                              void* d_out, int out_size, void* d_ws, size_t ws_size,
                              hipStream_t stream)
{
    const float* x  = (const float*)d_in[0];
    const float* Wq = (const float*)d_in[1];
    const float* bq = (const float*)d_in[2];
    const float* Wk = (const float*)d_in[3];
    const float* bk = (const float*)d_in[4];
    const float* Wv = (const float*)d_in[5];
    const float* bv = (const float*)d_in[6];
    float* out = (float*)d_out;

    char* ws = (char*)d_ws;
    _Float16* Qh = (_Float16*)ws;              // [16384][1024] fp16
    _Float16* Kh = Qh + 16777216;              // [16384][1024] fp16
    unsigned short* Vt = (unsigned short*)(Kh + 16777216);  // 8 x [1024][2048] bf16
    char* region = ws + 100663296;             // (xh+Wt) then E
    _Float16* xh = (_Float16*)region;          // [16384][1024] fp16 (dead after QKV)
    _Float16* Wt = xh + 16777216;              // [3072][1024] fp16  (dead after QKV)
    unsigned short* E = (unsigned short*)region;  // c x [2048][2048] bf16

    // chunk c: region = max(xh+Wt = 39845888, c*8388608); + rowsum 64KB
    int c = 8;
    size_t region_sz;
    for (;;) {
        region_sz = (size_t)c * 8388608ull;
        if (region_sz < 39845888ull) region_sz = 39845888ull;
        if (100663296ull + region_sz + 65536ull <= ws_size || c == 1) break;
        c >>= 1;
    }
    float* rowsum = (float*)(ws + 100663296 + region_sz);   // c x 2048 fp32

    static bool attr_done = false;
    if (!attr_done) {
        hipFuncSetAttribute((const void*)gemm_qkv8,
                            hipFuncAttributeMaxDynamicSharedMemorySize, 131072);
        hipFuncSetAttribute((const void*)gemm_sc8,
                            hipFuncAttributeMaxDynamicSharedMemorySize, 131072);
        hipFuncSetAttribute((const void*)gemm_pv8,
                            hipFuncAttributeMaxDynamicSharedMemorySize, 131072);
        attr_done = true;
    }

    cvt_f2h<<<2048, 256, 0, stream>>>(x, xh, 16777216 / 4);
    transpose_w<<<dim3(32, 32, 3), dim3(32, 8, 1), 0, stream>>>(Wq, Wk, Wv, Wt);
    gemm_qkv8<<<dim3(12, 64, 1), 512, 131072, stream>>>(
        (const unsigned short*)xh, (const unsigned short*)Wt, bq, bk, bv, Qh, Kh, Vt);

    for (int b0 = 0; b0 < 8; b0 += c) {
        int cc = (8 - b0 < c) ? (8 - b0) : c;
        hipMemsetAsync(rowsum, 0, (size_t)cc * 2048 * 4, stream);
        gemm_sc8<<<dim3(8, 8, cc), 512, 131072, stream>>>(
            (const unsigned short*)(Qh + (long)b0 * 2097152),
            (const unsigned short*)(Kh + (long)b0 * 2097152), E, rowsum);
        gemm_pv8<<<dim3(4, 8, cc), 512, 131072, stream>>>(
            E, Vt + (long)b0 * 2097152, rowsum, out + (long)b0 * 2097152);
    }
}